// Round 3
// baseline (279.487 us; speedup 1.0000x reference)
//
#include <hip/hip_runtime.h>
#include <hip/hip_bf16.h>
#include <math.h>

#define Bn 8
#define Tn 2048
#define Cn 1024
#define Hn 64
#define BTHb ((size_t)Bn * Tn * Hn)   // elements per projected matrix (bf16)

typedef __attribute__((ext_vector_type(8))) short bf16x8;
typedef __attribute__((ext_vector_type(4))) float f32x4;

static __device__ __forceinline__ unsigned short bf16rne(float f) {
    union { float f; unsigned u; } x; x.f = f;
    return (unsigned short)((x.u + 0x7FFFu + ((x.u >> 16) & 1u)) >> 16);
}

// HW round-to-nearest-even f32->bf16 (compiler pairs into v_cvt_pk_bf16_f32)
static __device__ __forceinline__ unsigned short hwbf16(float f) {
    union { __hip_bfloat16 h; unsigned short u; } c;
    c.h = __float2bfloat16(f);
    return c.u;
}

static __device__ __forceinline__ bf16x8 cvt8(const float4 a, const float4 b) {
    bf16x8 r;
    r[0] = (short)hwbf16(a.x); r[1] = (short)hwbf16(a.y);
    r[2] = (short)hwbf16(a.z); r[3] = (short)hwbf16(a.w);
    r[4] = (short)hwbf16(b.x); r[5] = (short)hwbf16(b.y);
    r[6] = (short)hwbf16(b.z); r[7] = (short)hwbf16(b.w);
    return r;
}

// async global->LDS, 16B per lane; dest = wave-uniform base + lane*16
#define GLOAD16(gsrc, ldst)                                                  \
    __builtin_amdgcn_global_load_lds(                                        \
        (const __attribute__((address_space(1))) void*)(gsrc),               \
        (__attribute__((address_space(3))) void*)(ldst), 16, 0, 0)

// ---------------------------------------------------------------------------
// MFMA projection -> bf16 output: O[row,h] = sum_c X[row,c] * W[h,c]
// grid (256, 3); block 256 = 4 waves; 64 rows x 64 h per block.
// v4: X and W staged fp32 directly to LDS via global_load_lds (no register
// round-trip -- v2/v3 showed the compiler collapses register prefetch to
// depth 1). Raw s_barrier + counted "s_waitcnt vmcnt(8)" keeps chunk c+1's
// 8 loads in flight across chunk c's barriers (a __syncthreads would drain
// vmcnt(0)). fp32->bf16 conversion happens at LDS->register fragment read
// using HW RNE cvt. Destination LDS must be linear (global_load_lds writes
// base+lane*16), so bank conflicts are fixed by XOR-swizzling the GLOBAL
// source column unit with (row&7) and applying the same XOR on the read
// side -- same conflict profile as a padded [64][72] layout.
// ---------------------------------------------------------------------------
__global__ __launch_bounds__(256) void proj_kernel(
    const float* __restrict__ k, const float* __restrict__ q,
    const float* __restrict__ v,
    const float* __restrict__ Wk, const float* __restrict__ Wq,
    const float* __restrict__ Wv,
    unsigned short* __restrict__ ws)
{
    const int which = blockIdx.y;
    const float* X = (which == 0) ? k : (which == 1) ? q : v;
    const float* W = (which == 0) ? Wk : (which == 1) ? Wq : Wv;
    unsigned short* O = ws + (size_t)which * BTHb;

    __shared__ float Xs[2][64][64];   // [buf][row][col] fp32, 16 KB each
    __shared__ float Wf[2][64][64];

    const int tid  = threadIdx.x;
    const int wave = __builtin_amdgcn_readfirstlane(tid >> 6);
    const int lane = tid & 63;
    const int m    = lane & 15;
    const int quad = lane >> 4;
    const int row0 = blockIdx.x * 64;

    // staging source pointers: instr i covers rows wave*16+i*4 + (lane>>4),
    // 16B unit (lane&15), XOR-swizzled by (row&7) so linear LDS dest ends up
    // swizzled. (i*4+lrow)&7 == lrow + 4*(i&1).
    const int lrow = lane >> 4, lcol = lane & 15;
    const float* xsrc[4];
    const float* wsrc[4];
#pragma unroll
    for (int i = 0; i < 4; ++i) {
        const int swz = lcol ^ ((i * 4 + lrow) & 7);
        xsrc[i] = X + (size_t)(row0 + wave * 16 + i * 4 + lrow) * Cn + swz * 4;
        wsrc[i] = W + (size_t)(wave * 16 + i * 4 + lrow) * Cn + swz * 4;
    }

    // read-side swizzled 16B-unit slots (within a K=32 chunk: units 2q, 2q+1)
    const int s0 = (2 * quad) ^ (m & 7);
    const int s1 = s0 ^ 1;

    f32x4 acc[4];
#pragma unroll
    for (int t = 0; t < 4; ++t) acc[t] = (f32x4){0.f, 0.f, 0.f, 0.f};

#define STAGE(p, ct)                                                         \
    do {                                                                     \
        _Pragma("unroll")                                                    \
        for (int i = 0; i < 4; ++i) {                                        \
            GLOAD16(xsrc[i] + (ct) * 64, &Xs[p][wave * 16 + i * 4][0]);      \
            GLOAD16(wsrc[i] + (ct) * 64, &Wf[p][wave * 16 + i * 4][0]);      \
        }                                                                    \
    } while (0)

#define COMPUTE(p)                                                           \
    do {                                                                     \
        _Pragma("unroll")                                                    \
        for (int kc = 0; kc < 2; ++kc) {                                     \
            const float4 xa0 =                                               \
                *(const float4*)&Xs[p][wave * 16 + m][(kc * 8 + s0) * 4];    \
            const float4 xa1 =                                               \
                *(const float4*)&Xs[p][wave * 16 + m][(kc * 8 + s1) * 4];    \
            const bf16x8 a = cvt8(xa0, xa1);                                 \
            _Pragma("unroll")                                                \
            for (int ht = 0; ht < 4; ++ht) {                                 \
                const float4 wb0 =                                           \
                    *(const float4*)&Wf[p][ht * 16 + m][(kc * 8 + s0) * 4];  \
                const float4 wb1 =                                           \
                    *(const float4*)&Wf[p][ht * 16 + m][(kc * 8 + s1) * 4];  \
                acc[ht] = __builtin_amdgcn_mfma_f32_16x16x32_bf16(           \
                    a, cvt8(wb0, wb1), acc[ht], 0, 0, 0);                    \
            }                                                                \
        }                                                                    \
    } while (0)

    STAGE(0, 0);   // chunk 0 in flight (8 loads/wave)

#pragma unroll
    for (int c = 0; c < 16; ++c) {
        if (c + 1 < 16) {
            STAGE((c + 1) & 1, c + 1);                  // 16 outstanding
            asm volatile("s_waitcnt vmcnt(8)" ::: "memory");  // chunk c done
        } else {
            asm volatile("s_waitcnt vmcnt(0)" ::: "memory");
        }
        __builtin_amdgcn_s_barrier();       // all waves' chunk-c data landed
        __builtin_amdgcn_sched_barrier(0);  // no ds_read hoists above barrier
        COMPUTE(c & 1);
        asm volatile("s_waitcnt lgkmcnt(0)" ::: "memory");
        __builtin_amdgcn_s_barrier();       // all waves done reading buffer
        __builtin_amdgcn_sched_barrier(0);
    }

#undef STAGE
#undef COMPUTE

    // D layout: col=lane&15, row=quad*4+reg
#pragma unroll
    for (int ht = 0; ht < 4; ++ht)
#pragma unroll
        for (int r = 0; r < 4; ++r)
            O[(size_t)(row0 + wave * 16 + quad * 4 + r) * Hn + ht * 16 + m] =
                bf16rne(acc[ht][r]);
}

// ---------------------------------------------------------------------------
// MFMA flash attention. grid (32, 8); block 256 = 4 waves.
// Block bx = q-tile of 64 rows (qt*64..+64); wave w owns rows wrb..wrb+16.
// k-loop j = 0..qt over 64-key tiles: stage K (row-major) + V^T (dim-major)
// bf16 in LDS, QK^T via 16x16x32 MFMA (4 col-tiles x 2 k-chunks), online
// softmax in C-layout registers, P -> LDS (bf16) -> A-frag, PV via MFMA.
// ---------------------------------------------------------------------------
__global__ __launch_bounds__(256) void attn_kernel(
    const unsigned short* __restrict__ ws,
    const int* __restrict__ mask,
    float* __restrict__ out)
{
    const unsigned short* kh = ws;
    const unsigned short* qh = ws + BTHb;
    const unsigned short* vh = ws + 2 * BTHb;

    const int b   = blockIdx.y;
    const int qt  = blockIdx.x;
    const int tid = threadIdx.x;
    const int wave = __builtin_amdgcn_readfirstlane(tid >> 6);
    const int lane = tid & 63;
    const int ln   = lane & 15;
    const int quad = lane >> 4;

    __shared__ unsigned short Ks[64][72];   // [kpos][dim]
    __shared__ unsigned short Vt[64][72];   // [dim][kpos]
    __shared__ unsigned short Ps[64][72];   // [q-row local][kpos]
    __shared__ int Msk[64];

    const int wrb = qt * 64 + wave * 16;    // wave's first q-row

    // Q A-frags: A[m=ln][k=quad*8+j], 2 chunks of K=32
    bf16x8 qa[2];
#pragma unroll
    for (int kc = 0; kc < 2; ++kc)
        qa[kc] = *(const bf16x8*)(qh + ((size_t)b * Tn + wrb + ln) * Hn
                                     + kc * 32 + quad * 8);

    f32x4 oacc[4];
#pragma unroll
    for (int t = 0; t < 4; ++t) oacc[t] = (f32x4){0.f, 0.f, 0.f, 0.f};
    float mrow[4] = {-1e30f, -1e30f, -1e30f, -1e30f};
    float lrow[4] = {0.f, 0.f, 0.f, 0.f};

    // staging: K by (row=tid>>2, seg=tid&3)  [coalesced global, b128 LDS]
    //          V by (col=tid&63, seg=tid>>6) [conflict-free transpose writes]
    const int krow = tid >> 2, kseg = tid & 3;
    const int vcol = tid & 63, vseg = tid >> 6;

    uint4 kreg[2], vreg[2];
    int mreg = 0;
    {
        const unsigned short* kp =
            kh + ((size_t)b * Tn + krow) * Hn + kseg * 16;
        kreg[0] = *(const uint4*)kp;
        kreg[1] = *(const uint4*)(kp + 8);
        const unsigned short* vp =
            vh + ((size_t)b * Tn + vcol) * Hn + vseg * 16;
        vreg[0] = *(const uint4*)vp;
        vreg[1] = *(const uint4*)(vp + 8);
        if (tid < 64) mreg = mask[(size_t)b * Tn + tid];
    }

    for (int j = 0; j <= qt; ++j) {
        __syncthreads();   // previous tile's LDS readers done
        *(uint4*)&Ks[krow][kseg * 16]     = kreg[0];
        *(uint4*)&Ks[krow][kseg * 16 + 8] = kreg[1];
        {
            const unsigned short* vs = (const unsigned short*)vreg;
#pragma unroll
            for (int jj = 0; jj < 16; ++jj)
                Vt[vseg * 16 + jj][vcol] = vs[jj];
        }
        if (tid < 64) Msk[tid] = mreg;
        __syncthreads();   // staged tile visible

        if (j < qt) {      // prefetch next tile; latency overlaps compute
            const unsigned short* kp =
                kh + ((size_t)b * Tn + (j + 1) * 64 + krow) * Hn + kseg * 16;
            kreg[0] = *(const uint4*)kp;
            kreg[1] = *(const uint4*)(kp + 8);
            const unsigned short* vp =
                vh + ((size_t)b * Tn + (j + 1) * 64 + vcol) * Hn + vseg * 16;
            vreg[0] = *(const uint4*)vp;
            vreg[1] = *(const uint4*)(vp + 8);
            if (tid < 64) mreg = mask[(size_t)b * Tn + (j + 1) * 64 + tid];
        }

        // ---- S = Q K^T : 4 col-tiles (16 kpos each) x 2 K-chunks ----
        f32x4 sacc[4];
#pragma unroll
        for (int t = 0; t < 4; ++t) sacc[t] = (f32x4){0.f, 0.f, 0.f, 0.f};
#pragma unroll
        for (int kc = 0; kc < 2; ++kc) {
#pragma unroll
            for (int nt = 0; nt < 4; ++nt) {
                const bf16x8 kb =
                    *(const bf16x8*)&Ks[nt * 16 + ln][kc * 32 + quad * 8];
                sacc[nt] = __builtin_amdgcn_mfma_f32_16x16x32_bf16(
                    qa[kc], kb, sacc[nt], 0, 0, 0);
            }
        }

        // ---- online softmax in C-layout (rows quad*4+r, col nt*16+ln) ----
        const bool fullv = (j < qt);   // tile fully causal-valid for block
        float pv[4][4];
        float mt[4] = {-1e30f, -1e30f, -1e30f, -1e30f};
#pragma unroll
        for (int nt = 0; nt < 4; ++nt) {
            const bool mk = (Msk[nt * 16 + ln] != 0);
            const int kpos = j * 64 + nt * 16 + ln;
#pragma unroll
            for (int r = 0; r < 4; ++r) {
                float s = sacc[nt][r] * 0.125f;
                const bool valid =
                    mk && (fullv || kpos <= wrb + quad * 4 + r);
                s = valid ? s : -1e30f;
                pv[nt][r] = s;
                mt[r] = fmaxf(mt[r], s);
            }
        }
#pragma unroll
        for (int r = 0; r < 4; ++r) {
            mt[r] = fmaxf(mt[r], __shfl_xor(mt[r], 1));
            mt[r] = fmaxf(mt[r], __shfl_xor(mt[r], 2));
            mt[r] = fmaxf(mt[r], __shfl_xor(mt[r], 4));
            mt[r] = fmaxf(mt[r], __shfl_xor(mt[r], 8));
        }
        float alpha[4], rsum[4];
#pragma unroll
        for (int r = 0; r < 4; ++r) {
            const float mn = fmaxf(mrow[r], mt[r]);
            alpha[r] = __expf(mrow[r] - mn);
            mrow[r] = mn;
            rsum[r] = 0.f;
        }
#pragma unroll
        for (int nt = 0; nt < 4; ++nt)
#pragma unroll
            for (int r = 0; r < 4; ++r) {
                const float p = (pv[nt][r] <= -1e29f)
                                    ? 0.f
                                    : __expf(pv[nt][r] - mrow[r]);
                pv[nt][r] = p;
                rsum[r] += p;
            }
#pragma unroll
        for (int r = 0; r < 4; ++r) {
            rsum[r] += __shfl_xor(rsum[r], 1);
            rsum[r] += __shfl_xor(rsum[r], 2);
            rsum[r] += __shfl_xor(rsum[r], 4);
            rsum[r] += __shfl_xor(rsum[r], 8);
            lrow[r] = lrow[r] * alpha[r] + rsum[r];
        }
#pragma unroll
        for (int nt = 0; nt < 4; ++nt)
#pragma unroll
            for (int r = 0; r < 4; ++r) oacc[nt][r] *= alpha[r];

        // ---- P -> LDS (bf16), wave-private region ----
#pragma unroll
        for (int nt = 0; nt < 4; ++nt)
#pragma unroll
            for (int r = 0; r < 4; ++r)
                Ps[wave * 16 + quad * 4 + r][nt * 16 + ln] =
                    bf16rne(pv[nt][r]);
        // wave-private LDS round-trip: drain DS writes, keep vmcnt in flight
        asm volatile("s_waitcnt lgkmcnt(0)" ::: "memory");

        // ---- O += P V : A=P[m=ln][k], B=V^T[n=dim][k] ----
#pragma unroll
        for (int kc = 0; kc < 2; ++kc) {
            const bf16x8 pa =
                *(const bf16x8*)&Ps[wave * 16 + ln][kc * 32 + quad * 8];
#pragma unroll
            for (int nt = 0; nt < 4; ++nt) {
                const bf16x8 vb =
                    *(const bf16x8*)&Vt[nt * 16 + ln][kc * 32 + quad * 8];
                oacc[nt] = __builtin_amdgcn_mfma_f32_16x16x32_bf16(
                    pa, vb, oacc[nt], 0, 0, 0);
            }
        }
    }

    // ---- epilogue: divide by l, fp32 store ----
#pragma unroll
    for (int r = 0; r < 4; ++r) {
        const float inv = 1.0f / lrow[r];
        const size_t rowoff = ((size_t)b * Tn + wrb + quad * 4 + r) * Hn;
#pragma unroll
        for (int nt = 0; nt < 4; ++nt)
            out[rowoff + nt * 16 + ln] = oacc[nt][r] * inv;
    }
}

extern "C" void kernel_launch(void* const* d_in, const int* in_sizes, int n_in,
                              void* d_out, int out_size, void* d_ws, size_t ws_size,
                              hipStream_t stream)
{
    const float* k    = (const float*)d_in[0];
    const float* q    = (const float*)d_in[1];
    const float* v    = (const float*)d_in[2];
    const int*   mask = (const int*)d_in[3];
    const float* Wk   = (const float*)d_in[4];
    const float* Wq   = (const float*)d_in[5];
    const float* Wv   = (const float*)d_in[6];
    float* out = (float*)d_out;
    unsigned short* ws = (unsigned short*)d_ws;  // kh|qh|vh bf16, 6.3 MB

    dim3 pb(256), pg(Bn * Tn / 64, 3);
    proj_kernel<<<pg, pb, 0, stream>>>(k, q, v, Wk, Wq, Wv, ws);

    dim3 ab(256), ag(Tn / 64, Bn);
    attn_kernel<<<ag, ab, 0, stream>>>(ws, mask, out);
}